// Round 15
// baseline (94.157 us; speedup 1.0000x reference)
//
#include <hip/hip_runtime.h>
#include <cfloat>

typedef unsigned short u16;
typedef unsigned int u32;
typedef u16   u16x4 __attribute__((ext_vector_type(4)));
typedef float f32x4 __attribute__((ext_vector_type(4)));
typedef _Float16 f16x8 __attribute__((ext_vector_type(8)));

// lexicographic (value, index) less — matches argmin lowest-index tie-break
__device__ __forceinline__ bool vless(float v, int i, float v2, int i2) {
  return v < v2 || (v == v2 && i < i2);
}

// monotonic float->uint map (order-preserving for all finite floats)
__device__ __forceinline__ u32 fmono(float f) {
  u32 u = __float_as_uint(f);
  return u ^ (0x80000000u | (u32)((int)u >> 31));
}
__device__ __forceinline__ float fmono_inv(u32 m) {
  u32 u = (m & 0x80000000u) ? (m ^ 0x80000000u) : ~m;
  return __uint_as_float(u);
}

// ---------------------------------------------------------------------------
// Pretile a [R,512] fp32 matrix into FRAGMENT-MAJOR f16 panels (+c2 +copy).
// Panel unit: (tile of 128 rows, 64-k slice s) = 16 KB; 16 fragments of 1 KB.
// Fragment (rb,h): rows rb*16..+15, k h*32..+31. Lane (kgrp*16+lrow) holds
// row lrow's k kgrp*8..+7 at frag_base + lane*16 — the exact MFMA operand
// order, so a global_load_dwordx4 at frag+lane*16 IS the operand fetch.
__global__ __launch_bounds__(128) void vq_prep(
    const float* __restrict__ src, u16* __restrict__ pan,
    float* __restrict__ sq, float* __restrict__ copy_out) {
  __shared__ float red[2];
  const int row_g = blockIdx.x;
  const int t = threadIdx.x;             // 0..127, 4 floats each
  float4 v = reinterpret_cast<const float4*>(src + (size_t)row_g * 512)[t];
  if (copy_out)
    reinterpret_cast<float4*>(copy_out + (size_t)row_g * 512)[t] = v;
  float f[4] = {v.x, v.y, v.z, v.w};
  u16 q[4];
  #pragma unroll
  for (int i = 0; i < 4; ++i)
    q[i] = __builtin_bit_cast(u16, (_Float16)f[i]);   // RNE
  const int d = t * 4;
  const int tile = row_g >> 7, r = row_g & 127;
  const int rb = r >> 4, lrow = r & 15;
  const int s = d >> 6, kk = d & 63, h = kk >> 5, kkl = kk & 31;
  const int kgrp = kkl >> 3, e = kkl & 7;
  const size_t off = ((size_t)(tile * 8 + s)) * 16384 +
      (size_t)((rb * 2 + h) * 1024 + (kgrp * 16 + lrow) * 16 + e * 2);
  u16x4 tq = {q[0], q[1], q[2], q[3]};
  *reinterpret_cast<u16x4*>((char*)pan + off) = tq;
  if (sq) {
    float ssum = v.x*v.x + v.y*v.y + v.z*v.z + v.w*v.w;
    #pragma unroll
    for (int m = 1; m < 64; m <<= 1) ssum += __shfl_xor(ssum, m);
    if ((t & 63) == 0) red[t >> 6] = ssum;
    __syncthreads();
    if (t == 0) sq[row_g] = red[0] + red[1];
  }
}

// ---------------------------------------------------------------------------
// Screening GEMM + per-64-col-subtile TOP-2 (packed-key) argmin.
// ZERO-LDS FREE-RUN: tile 128x128, 4 waves (2x2), per-wave 64x64.
// BOTH operands read direct global->register from fragment-major panels
// (frag + lane*16), JIT per k-half. No __shared__, no __syncthreads, no
// staging — waves free-run (R6 ablation M3: reads hide under MFMA when
// unconstrained). B panel is L2-resident (2 MB); A band L2-local per XCD.
// score = c2[col] - 2*dot (x2 row-constant, dropped for argmin).
template <int PANEL_A>
__global__ __launch_bounds__(256, 4) void vq_gemm(
    const float* __restrict__ X,
    const u16* __restrict__ Apan, const u16* __restrict__ Bpan,
    const float* __restrict__ c2,
    float4* __restrict__ part, int nnt) {
  const int tid = threadIdx.x;
  const int lane = tid & 63, wid = tid >> 6;   // 4 waves
  const int wm = wid >> 1, wn = wid & 1;       // 2 x 2
  const int nwg = gridDim.x;
  const int bid = blockIdx.x;
  const int swb = (bid & 7) * (nwg >> 3) + (bid >> 3);  // XCD band swizzle
  const int mtile = swb / nnt, ntile = swb % nnt;
  const int lrow = lane & 15, kgrp = lane >> 4;
  const int rot = bid & 7;                     // L2-decorrelating rotation
  f32x4 acc[4][4] = {};

  const char* gA = (const char*)Apan + ((size_t)mtile * 8) * 16384 + lane * 16;
  const char* gB = (const char*)Bpan + ((size_t)ntile * 8) * 16384 + lane * 16;
  // fallback: per-lane f32 row base (row = mtile*128 + wm*64 + t2*16 + lrow)
  const float* xbase =
      X + ((size_t)(mtile * 128 + wm * 64 + lrow)) * 512 + kgrp * 8;

  #pragma unroll 1
  for (int s = 0; s < 8; ++s) {
    const int p = (s + rot) & 7;
    const char* ap = gA + (size_t)p * 16384;
    const char* bp = gB + (size_t)p * 16384;
    #pragma unroll
    for (int h = 0; h < 2; ++h) {
      f16x8 a[4];
      if constexpr (PANEL_A) {
        #pragma unroll
        for (int t2 = 0; t2 < 4; ++t2)
          a[t2] = *reinterpret_cast<const f16x8*>(
              ap + ((wm * 4 + t2) * 2 + h) * 1024);
      } else {
        const float* xp = xbase + p * 64 + h * 32;
        #pragma unroll
        for (int t2 = 0; t2 < 4; ++t2) {
          const float4 f0 = *reinterpret_cast<const float4*>(xp + (size_t)t2 * 8192);
          const float4 f1 = *reinterpret_cast<const float4*>(xp + (size_t)t2 * 8192 + 4);
          f16x8 av;
          av[0] = (_Float16)f0.x; av[1] = (_Float16)f0.y;
          av[2] = (_Float16)f0.z; av[3] = (_Float16)f0.w;
          av[4] = (_Float16)f1.x; av[5] = (_Float16)f1.y;
          av[6] = (_Float16)f1.z; av[7] = (_Float16)f1.w;
          a[t2] = av;
        }
      }
      __builtin_amdgcn_s_setprio(1);
      #pragma unroll
      for (int u = 0; u < 4; ++u) {
        const f16x8 b = *reinterpret_cast<const f16x8*>(
            bp + ((wn * 4 + u) * 2 + h) * 1024);
        #pragma unroll
        for (int i = 0; i < 4; ++i)
          acc[i][u] = __builtin_amdgcn_mfma_f32_16x16x32_f16(a[i], b, acc[i][u], 0, 0, 0);
      }
      __builtin_amdgcn_s_setprio(0);
    }
  }

  // ---- epilogue: per-row TOP-2 over this wave's 64 cols via packed keys.
  // key = (monotonic(score) & ~0x7FF) | col. Quantization absorbed by the
  // final margin (1.0).
  float c2v[4];
  #pragma unroll
  for (int j = 0; j < 4; ++j) c2v[j] = c2[ntile * 128 + wn * 64 + j * 16 + lrow];
  #pragma unroll
  for (int i = 0; i < 4; ++i) {
    #pragma unroll
    for (int jj = 0; jj < 4; ++jj) {
      u32 k1 = 0xFFFFFFFFu, k2 = 0xFFFFFFFFu;
      #pragma unroll
      for (int j = 0; j < 4; ++j) {
        const float sc = c2v[j] - 2.0f * acc[i][j][jj];
        const u32 col = (u32)(ntile * 128 + wn * 64 + j * 16 + lrow);
        const u32 k = (fmono(sc) & 0xFFFFF800u) | col;
        if (k < k1) { k2 = k1; k1 = k; } else if (k < k2) { k2 = k; }
      }
      #pragma unroll
      for (int m = 1; m < 16; m <<= 1) {
        const u32 ok1 = (u32)__shfl_xor((int)k1, m);
        const u32 ok2 = (u32)__shfl_xor((int)k2, m);
        const u32 lo = min(k1, ok1), hi = max(k1, ok1);
        k1 = lo;
        k2 = min(hi, min(k2, ok2));
      }
      if (lrow == 0) {
        const int row = mtile * 128 + wm * 64 + i * 16 + kgrp * 4 + jj;
        part[(size_t)row * 32 + (ntile * 2 + wn)] =
            make_float4(fmono_inv(k1 & 0xFFFFF800u), __int_as_float((int)(k1 & 0x7FFu)),
                        fmono_inv(k2 & 0xFFFFF800u), __int_as_float((int)(k2 & 0x7FFu)));
      }
    }
  }
}

// ---------------------------------------------------------------------------
// Final: global approx argmin over 64 stored candidates/row; margin-flag;
// exact double-precision refine when >1 candidate within margin; outputs.
__global__ __launch_bounds__(256) void vq_final(
    const float* __restrict__ X, const float* __restrict__ CB,
    const float4* __restrict__ part,
    float* __restrict__ out0, float* __restrict__ out1, float* __restrict__ out2) {
  const int row = blockIdx.x * 4 + (threadIdx.x >> 6);
  const int l = threadIdx.x & 63;
  const float4 p = part[(size_t)row * 32 + (l >> 1)];
  const float v = (l & 1) ? p.z : p.x;
  const int ci = __float_as_int((l & 1) ? p.w : p.y);
  float rv = v; int ri = ci;
  #pragma unroll
  for (int m = 1; m < 64; m <<= 1) {
    const float ov = __shfl_xor(rv, m);
    const int oi = __shfl_xor(ri, m);
    if (vless(ov, oi, rv, ri)) { rv = ov; ri = oi; }
  }
  int idx;
  unsigned long long mask = __ballot(v <= rv + 1.0f);   // margin (f16 err + key quant)
  if (__popcll(mask) == 1) {
    idx = ri;                                            // certain winner
  } else {
    float xr[8];
    #pragma unroll
    for (int e = 0; e < 8; ++e) xr[e] = X[(size_t)row * 512 + l + e * 64];
    double bd = 1e300; int bi = 0x7fffffff;
    while (mask) {
      const int sl = __ffsll((long long)mask) - 1;
      mask &= mask - 1;
      const int cidx = __shfl(ci, sl);
      double accd = 0.0;
      #pragma unroll
      for (int e = 0; e < 8; ++e) {
        const double dd = (double)xr[e] - (double)CB[(size_t)cidx * 512 + l + e * 64];
        accd += dd * dd;
      }
      #pragma unroll
      for (int m = 1; m < 64; m <<= 1) accd += __shfl_xor(accd, m);
      if (accd < bd || (accd == bd && cidx < bi)) { bd = accd; bi = cidx; }
    }
    idx = bi;
  }
  const float4* xr4 = reinterpret_cast<const float4*>(X + (size_t)row * 512);
  const float4* cr4 = reinterpret_cast<const float4*>(CB + (size_t)idx * 512);
  float4* q  = reinterpret_cast<float4*>(out0 + (size_t)row * 512);
  float4* ls = reinterpret_cast<float4*>(out1 + (size_t)row * 512);
  #pragma unroll
  for (int pp = 0; pp < 2; ++pp) {
    const int e = l + 64 * pp;
    const float4 xv = xr4[e], cv = cr4[e];
    float4 d4, qv, lv;
    d4.x = cv.x - xv.x; d4.y = cv.y - xv.y; d4.z = cv.z - xv.z; d4.w = cv.w - xv.w;
    qv.x = xv.x + d4.x; qv.y = xv.y + d4.y; qv.z = xv.z + d4.z; qv.w = xv.w + d4.w;
    lv.x = d4.x * d4.x; lv.y = d4.y * d4.y; lv.z = d4.z * d4.z; lv.w = d4.w * d4.w;
    q[e] = qv; ls[e] = lv;
  }
  if (l == 0) out2[row] = (float)idx;
}

extern "C" void kernel_launch(void* const* d_in, const int* in_sizes, int n_in,
                              void* d_out, int out_size, void* d_ws, size_t ws_size,
                              hipStream_t stream) {
  const float* X  = (const float*)d_in[0];   // [M,512] fp32
  const float* CB = (const float*)d_in[1];   // [K,512] fp32
  const int D = 512;
  const int M = in_sizes[0] / D;             // 16384
  const int K = in_sizes[1] / D;             // 2048
  float* out0 = (float*)d_out;               // quantized_ste [M,512]
  float* out1 = out0 + (size_t)M * D;        // loss          [M,512]
  float* out2 = out1 + (size_t)M * D;        // nn_idx (as f32) [M]
  float* out3 = out2 + M;                    // codebook copy [K,512]

  char* ws = (char*)d_ws;
  size_t off = 0;
  u16* Bpan = (u16*)(ws + off); off += (size_t)K * D * 2;     // f16 fragment panels
  float* c2 = (float*)(ws + off); off += (size_t)K * 4;
  float4* part = (float4*)(ws + off); off += (size_t)M * 32 * 16;
  u16* Apan = (u16*)(ws + off);
  const size_t need_big = off + (size_t)M * D * 2;
  const bool big = (ws_size >= need_big);

  vq_prep<<<K, 128, 0, stream>>>(CB, Bpan, c2, out3);
  const int nmt = M / 128, nnt = K / 128;                     // 128 x 16
  const int nwg = nmt * nnt;                                  // 2048
  if (big) {
    vq_prep<<<M, 128, 0, stream>>>(X, Apan, nullptr, nullptr);
    vq_gemm<1><<<nwg, 256, 0, stream>>>(X, Apan, Bpan, c2, part, nnt);
  } else {
    vq_gemm<0><<<nwg, 256, 0, stream>>>(X, nullptr, Bpan, c2, part, nnt);
  }
  vq_final<<<M / 4, 256, 0, stream>>>(X, CB, part, out0, out1, out2);
}

// Round 16
// 93.819 us; speedup vs baseline: 1.0036x; 1.0036x over previous
//
#include <hip/hip_runtime.h>
#include <cfloat>

typedef unsigned short u16;
typedef unsigned int u32;
typedef u16   u16x4 __attribute__((ext_vector_type(4)));
typedef float f32x4 __attribute__((ext_vector_type(4)));
typedef _Float16 f16x8 __attribute__((ext_vector_type(8)));

// lexicographic (value, index) less — matches argmin lowest-index tie-break
__device__ __forceinline__ bool vless(float v, int i, float v2, int i2) {
  return v < v2 || (v == v2 && i < i2);
}

// monotonic float->uint map (order-preserving for all finite floats)
__device__ __forceinline__ u32 fmono(float f) {
  u32 u = __float_as_uint(f);
  return u ^ (0x80000000u | (u32)((int)u >> 31));
}
__device__ __forceinline__ float fmono_inv(u32 m) {
  u32 u = (m & 0x80000000u) ? (m ^ 0x80000000u) : ~m;
  return __uint_as_float(u);
}

// ---------------------------------------------------------------------------
// Pretile a [R,512] fp32 matrix into FRAGMENT-MAJOR f16 panels (+c2 +copy).
// Panel unit: (tile of 128 rows, 64-k slice s) = 16 KB; 16 fragments of 1 KB.
// Fragment (rb,h): rows rb*16..+15, k h*32..+31. Lane (kgrp*16+lrow) holds
// row lrow's k kgrp*8..+7 at frag_base + lane*16 — the exact MFMA operand
// order, so a global_load_dwordx4 at frag+lane*16 IS the operand fetch.
__global__ __launch_bounds__(128) void vq_prep(
    const float* __restrict__ src, u16* __restrict__ pan,
    float* __restrict__ sq, float* __restrict__ copy_out) {
  __shared__ float red[2];
  const int row_g = blockIdx.x;
  const int t = threadIdx.x;             // 0..127, 4 floats each
  float4 v = reinterpret_cast<const float4*>(src + (size_t)row_g * 512)[t];
  if (copy_out)
    reinterpret_cast<float4*>(copy_out + (size_t)row_g * 512)[t] = v;
  float f[4] = {v.x, v.y, v.z, v.w};
  u16 q[4];
  #pragma unroll
  for (int i = 0; i < 4; ++i)
    q[i] = __builtin_bit_cast(u16, (_Float16)f[i]);   // RNE
  const int d = t * 4;
  const int tile = row_g >> 7, r = row_g & 127;
  const int rb = r >> 4, lrow = r & 15;
  const int s = d >> 6, kk = d & 63, h = kk >> 5, kkl = kk & 31;
  const int kgrp = kkl >> 3, e = kkl & 7;
  const size_t off = ((size_t)(tile * 8 + s)) * 16384 +
      (size_t)((rb * 2 + h) * 1024 + (kgrp * 16 + lrow) * 16 + e * 2);
  u16x4 tq = {q[0], q[1], q[2], q[3]};
  *reinterpret_cast<u16x4*>((char*)pan + off) = tq;
  if (sq) {
    float ssum = v.x*v.x + v.y*v.y + v.z*v.z + v.w*v.w;
    #pragma unroll
    for (int m = 1; m < 64; m <<= 1) ssum += __shfl_xor(ssum, m);
    if ((t & 63) == 0) red[t >> 6] = ssum;
    __syncthreads();
    if (t == 0) sq[row_g] = red[0] + red[1];
  }
}

// ---------------------------------------------------------------------------
// Screening GEMM + per-64-col-subtile TOP-2 (packed-key) argmin.
// ZERO-LDS FREE-RUN + REGISTER DOUBLE-BUFFER. Tile 128x128, 4 waves (2x2),
// per-wave 64x64. Both operands direct global->reg from fragment-major
// panels. __launch_bounds__(256,3): 170-reg budget -> room for depth-1
// prefetch (chunk c+1's 8 loads issued before chunk c's 16 MFMAs) — hides
// L2 latency that the 128-reg/4-wave config could not (R14: 8 regs free,
// zero ILP, stuck at 54 us). 12 waves/CU, fully unrolled, no barriers.
// score = c2[col] - 2*dot (x2 row-constant, dropped for argmin).
template <int PANEL_A>
__global__ __launch_bounds__(256, 3) void vq_gemm(
    const float* __restrict__ X,
    const u16* __restrict__ Apan, const u16* __restrict__ Bpan,
    const float* __restrict__ c2,
    float4* __restrict__ part, int nnt) {
  const int tid = threadIdx.x;
  const int lane = tid & 63, wid = tid >> 6;   // 4 waves
  const int wm = wid >> 1, wn = wid & 1;       // 2 x 2
  const int nwg = gridDim.x;
  const int bid = blockIdx.x;
  const int swb = (bid & 7) * (nwg >> 3) + (bid >> 3);  // XCD band swizzle
  const int mtile = swb / nnt, ntile = swb % nnt;
  const int lrow = lane & 15, kgrp = lane >> 4;
  const int rot = bid & 7;                     // L2-decorrelating rotation
  f32x4 acc[4][4] = {};

  const char* gA = (const char*)Apan + ((size_t)mtile * 8) * 16384 + lane * 16;
  const char* gB = (const char*)Bpan + ((size_t)ntile * 8) * 16384 + lane * 16;
  // fallback: per-lane f32 row base (row = mtile*128 + wm*64 + t2*16 + lrow)
  const float* xbase =
      X + ((size_t)(mtile * 128 + wm * 64 + lrow)) * 512 + kgrp * 8;

  // chunk c (0..15): k-slice p = (c>>1 + rot)&7, k-half h = c&1.
  auto loadChunk = [&](int c, f16x8* a, f16x8* b) {
    const int p = ((c >> 1) + rot) & 7;
    const int h = c & 1;
    const char* bp = gB + (size_t)p * 16384 + h * 1024;
    #pragma unroll
    for (int u = 0; u < 4; ++u)
      b[u] = *reinterpret_cast<const f16x8*>(bp + (wn * 4 + u) * 2048);
    if constexpr (PANEL_A) {
      const char* ap = gA + (size_t)p * 16384 + h * 1024;
      #pragma unroll
      for (int t2 = 0; t2 < 4; ++t2)
        a[t2] = *reinterpret_cast<const f16x8*>(ap + (wm * 4 + t2) * 2048);
    } else {
      const float* xp = xbase + p * 64 + h * 32;
      #pragma unroll
      for (int t2 = 0; t2 < 4; ++t2) {
        const float4 f0 = *reinterpret_cast<const float4*>(xp + (size_t)t2 * 8192);
        const float4 f1 = *reinterpret_cast<const float4*>(xp + (size_t)t2 * 8192 + 4);
        f16x8 av;
        av[0] = (_Float16)f0.x; av[1] = (_Float16)f0.y;
        av[2] = (_Float16)f0.z; av[3] = (_Float16)f0.w;
        av[4] = (_Float16)f1.x; av[5] = (_Float16)f1.y;
        av[6] = (_Float16)f1.z; av[7] = (_Float16)f1.w;
        a[t2] = av;
      }
    }
  };
  auto mfmaChunk = [&](const f16x8* a, const f16x8* b) {
    __builtin_amdgcn_s_setprio(1);
    #pragma unroll
    for (int u = 0; u < 4; ++u)
      #pragma unroll
      for (int i = 0; i < 4; ++i)
        acc[i][u] = __builtin_amdgcn_mfma_f32_16x16x32_f16(a[i], b[u], acc[i][u], 0, 0, 0);
    __builtin_amdgcn_s_setprio(0);
  };

  f16x8 a0[4], b0[4], a1[4], b1[4];
  loadChunk(0, a0, b0);
  #pragma unroll
  for (int it = 0; it < 8; ++it) {
    loadChunk(it * 2 + 1, a1, b1);   // prefetch next chunk
    mfmaChunk(a0, b0);               // compute current (loads arrived)
    if (it < 7) loadChunk(it * 2 + 2, a0, b0);
    mfmaChunk(a1, b1);
  }

  // ---- epilogue: per-row TOP-2 over this wave's 64 cols via packed keys.
  // key = (monotonic(score) & ~0x7FF) | col. Quantization absorbed by the
  // final margin (1.0).
  float c2v[4];
  #pragma unroll
  for (int j = 0; j < 4; ++j) c2v[j] = c2[ntile * 128 + wn * 64 + j * 16 + lrow];
  #pragma unroll
  for (int i = 0; i < 4; ++i) {
    #pragma unroll
    for (int jj = 0; jj < 4; ++jj) {
      u32 k1 = 0xFFFFFFFFu, k2 = 0xFFFFFFFFu;
      #pragma unroll
      for (int j = 0; j < 4; ++j) {
        const float sc = c2v[j] - 2.0f * acc[i][j][jj];
        const u32 col = (u32)(ntile * 128 + wn * 64 + j * 16 + lrow);
        const u32 k = (fmono(sc) & 0xFFFFF800u) | col;
        if (k < k1) { k2 = k1; k1 = k; } else if (k < k2) { k2 = k; }
      }
      #pragma unroll
      for (int m = 1; m < 16; m <<= 1) {
        const u32 ok1 = (u32)__shfl_xor((int)k1, m);
        const u32 ok2 = (u32)__shfl_xor((int)k2, m);
        const u32 lo = min(k1, ok1), hi = max(k1, ok1);
        k1 = lo;
        k2 = min(hi, min(k2, ok2));
      }
      if (lrow == 0) {
        const int row = mtile * 128 + wm * 64 + i * 16 + kgrp * 4 + jj;
        part[(size_t)row * 32 + (ntile * 2 + wn)] =
            make_float4(fmono_inv(k1 & 0xFFFFF800u), __int_as_float((int)(k1 & 0x7FFu)),
                        fmono_inv(k2 & 0xFFFFF800u), __int_as_float((int)(k2 & 0x7FFu)));
      }
    }
  }
}

// ---------------------------------------------------------------------------
// Final: global approx argmin over 64 stored candidates/row; margin-flag;
// exact double-precision refine when >1 candidate within margin; outputs.
__global__ __launch_bounds__(256) void vq_final(
    const float* __restrict__ X, const float* __restrict__ CB,
    const float4* __restrict__ part,
    float* __restrict__ out0, float* __restrict__ out1, float* __restrict__ out2) {
  const int row = blockIdx.x * 4 + (threadIdx.x >> 6);
  const int l = threadIdx.x & 63;
  const float4 p = part[(size_t)row * 32 + (l >> 1)];
  const float v = (l & 1) ? p.z : p.x;
  const int ci = __float_as_int((l & 1) ? p.w : p.y);
  float rv = v; int ri = ci;
  #pragma unroll
  for (int m = 1; m < 64; m <<= 1) {
    const float ov = __shfl_xor(rv, m);
    const int oi = __shfl_xor(ri, m);
    if (vless(ov, oi, rv, ri)) { rv = ov; ri = oi; }
  }
  int idx;
  unsigned long long mask = __ballot(v <= rv + 1.0f);   // margin (f16 err + key quant)
  if (__popcll(mask) == 1) {
    idx = ri;                                            // certain winner
  } else {
    float xr[8];
    #pragma unroll
    for (int e = 0; e < 8; ++e) xr[e] = X[(size_t)row * 512 + l + e * 64];
    double bd = 1e300; int bi = 0x7fffffff;
    while (mask) {
      const int sl = __ffsll((long long)mask) - 1;
      mask &= mask - 1;
      const int cidx = __shfl(ci, sl);
      double accd = 0.0;
      #pragma unroll
      for (int e = 0; e < 8; ++e) {
        const double dd = (double)xr[e] - (double)CB[(size_t)cidx * 512 + l + e * 64];
        accd += dd * dd;
      }
      #pragma unroll
      for (int m = 1; m < 64; m <<= 1) accd += __shfl_xor(accd, m);
      if (accd < bd || (accd == bd && cidx < bi)) { bd = accd; bi = cidx; }
    }
    idx = bi;
  }
  const float4* xr4 = reinterpret_cast<const float4*>(X + (size_t)row * 512);
  const float4* cr4 = reinterpret_cast<const float4*>(CB + (size_t)idx * 512);
  float4* q  = reinterpret_cast<float4*>(out0 + (size_t)row * 512);
  float4* ls = reinterpret_cast<float4*>(out1 + (size_t)row * 512);
  #pragma unroll
  for (int pp = 0; pp < 2; ++pp) {
    const int e = l + 64 * pp;
    const float4 xv = xr4[e], cv = cr4[e];
    float4 d4, qv, lv;
    d4.x = cv.x - xv.x; d4.y = cv.y - xv.y; d4.z = cv.z - xv.z; d4.w = cv.w - xv.w;
    qv.x = xv.x + d4.x; qv.y = xv.y + d4.y; qv.z = xv.z + d4.z; qv.w = xv.w + d4.w;
    lv.x = d4.x * d4.x; lv.y = d4.y * d4.y; lv.z = d4.z * d4.z; lv.w = d4.w * d4.w;
    q[e] = qv; ls[e] = lv;
  }
  if (l == 0) out2[row] = (float)idx;
}

extern "C" void kernel_launch(void* const* d_in, const int* in_sizes, int n_in,
                              void* d_out, int out_size, void* d_ws, size_t ws_size,
                              hipStream_t stream) {
  const float* X  = (const float*)d_in[0];   // [M,512] fp32
  const float* CB = (const float*)d_in[1];   // [K,512] fp32
  const int D = 512;
  const int M = in_sizes[0] / D;             // 16384
  const int K = in_sizes[1] / D;             // 2048
  float* out0 = (float*)d_out;               // quantized_ste [M,512]
  float* out1 = out0 + (size_t)M * D;        // loss          [M,512]
  float* out2 = out1 + (size_t)M * D;        // nn_idx (as f32) [M]
  float* out3 = out2 + M;                    // codebook copy [K,512]

  char* ws = (char*)d_ws;
  size_t off = 0;
  u16* Bpan = (u16*)(ws + off); off += (size_t)K * D * 2;     // f16 fragment panels
  float* c2 = (float*)(ws + off); off += (size_t)K * 4;
  float4* part = (float4*)(ws + off); off += (size_t)M * 32 * 16;
  u16* Apan = (u16*)(ws + off);
  const size_t need_big = off + (size_t)M * D * 2;
  const bool big = (ws_size >= need_big);

  vq_prep<<<K, 128, 0, stream>>>(CB, Bpan, c2, out3);
  const int nmt = M / 128, nnt = K / 128;                     // 128 x 16
  const int nwg = nmt * nnt;                                  // 2048
  if (big) {
    vq_prep<<<M, 128, 0, stream>>>(X, Apan, nullptr, nullptr);
    vq_gemm<1><<<nwg, 256, 0, stream>>>(X, Apan, Bpan, c2, part, nnt);
  } else {
    vq_gemm<0><<<nwg, 256, 0, stream>>>(X, nullptr, Bpan, c2, part, nnt);
  }
  vq_final<<<M / 4, 256, 0, stream>>>(X, CB, part, out0, out1, out2);
}